// Round 3
// baseline (213.407 us; speedup 1.0000x reference)
//
#include <hip/hip_runtime.h>
#include <hip/hip_bf16.h>

typedef __bf16 bf16x8 __attribute__((ext_vector_type(8)));
typedef float f32x16 __attribute__((ext_vector_type(16)));

#define NB 8
#define ND 512
#define NT 2048
#define NCODES 4096
#define NM (NB * NT)          // 16384 rows
#define MARGIN_F 0.2f
#define ENC_STRIDE 320

#define BM 128
#define BN 128
#define BK 64
#define NCHUNK 64             // 64-col chunks for the neg/pos partials

// Swizzled operand layout (both Z and Cb):
//   tile (R_, K_) = 128 rows x 64 k = 16 KB at byte offset ((R_*8 + K_)*16384)
//   chunk (g, ks) = 1024 B at (g*4 + ks)*1024 within tile   (g: 32-row group, ks: 16-k step)
//   lane l's 16 B at l*16: row = R_*128 + g*32 + (l&31), k = K_*64 + ks*16 + (l>>5)*8 + j (j=0..7)
// This is exactly the v_mfma_f32_32x32x16_bf16 A/B operand image, so GEMM frag
// loads are ds_read_b128 at (chunk*1024 + lane*16): conflict-free.

static __device__ inline unsigned short f2bf(float v) {
    __hip_bfloat16 h = __float2bfloat16(v);
    return __builtin_bit_cast(unsigned short, h);
}

static __device__ inline void async_copy16(const void* g, void* l) {
    __builtin_amdgcn_global_load_lds(
        (const __attribute__((address_space(1))) unsigned int*)g,
        (__attribute__((address_space(3))) unsigned int*)l, 16, 0, 0);
}

// ---- kernel 1: student (B,D,T) fp32 -> swizzled Z bf16, + partial norms ----
// block: 32 t x 64 d tile. npart[j = d0/64][m] = sum of z^2 over 64 d's.
__global__ void student_swz(const float* __restrict__ sf, unsigned short* __restrict__ Z,
                            float* __restrict__ npart) {
    __shared__ float tile[64][36];  // [d_local][t_local], pad 36: conflict-free both phases
    __shared__ float red[4][32];
    const int b = blockIdx.z;
    const int t0 = blockIdx.x * 32;
    const int d0 = blockIdx.y * 64;
    const int tid = threadIdx.x;  // 256
    const float* src = sf + (size_t)b * ND * NT;
    // phase 1: each thread 2x float4 along t (coalesced 128-B segments)
#pragma unroll
    for (int p = 0; p < 2; p++) {
        int d = p * 32 + (tid >> 3);
        int t4 = (tid & 7) * 4;
        float4 v = *(const float4*)(src + (size_t)(d0 + d) * NT + t0 + t4);
        *(float4*)&tile[d][t4] = v;  // b128, uniform bank spread
    }
    __syncthreads();
    // phase 2: wave w emits chunk ks=w; lane l: row t0+(l&31), k = d0 + w*16 + (l>>5)*8 + q
    const int wave = tid >> 6, lane = tid & 63, l31 = lane & 31, half = lane >> 5;
    float sq = 0.0f;
    unsigned short o[8];
#pragma unroll
    for (int q = 0; q < 8; q++) {
        float v = tile[wave * 16 + half * 8 + q][l31];
        sq += v * v;
        o[q] = f2bf(v);
    }
    const int mblk = b * NT + t0;  // = M_*128 + g*32
    const int M_ = mblk >> 7, g = (mblk >> 5) & 3, K_ = d0 >> 6;
    char* dst = (char*)Z + ((size_t)((M_ * 8 + K_) * 16 + g * 4 + wave)) * 1024 + lane * 16;
    *(uint4*)dst = *(uint4*)o;
    // norms: this lane covered 8 d's; pair-reduce halves, then 4 waves via LDS
    sq += __shfl_xor(sq, 32);
    if (half == 0) red[wave][l31] = sq;
    __syncthreads();
    if (tid < 32) {
        float zn = red[0][tid] + red[1][tid] + red[2][tid] + red[3][tid];
        npart[(size_t)(d0 >> 6) * NM + mblk + tid] = zn;
    }
}

// ---- kernel 2: codebook (NC,D) fp32 -> swizzled Cb bf16, + full row norms ----
#define CPAD 520  // LDS row stride in ushorts (1040 B: 16B-aligned, 4-way read alias only)
__global__ void codebook_swz(const float* __restrict__ cb, unsigned short* __restrict__ Cb,
                             float* __restrict__ cnorm) {
    __shared__ unsigned short ct[32 * CPAD];  // 33.3 KB bf16 [32 rows][512 k]
    __shared__ float red[32][128];            // 16 KB norm partials
    const int tid = threadIdx.x;  // 256
    const int R0 = blockIdx.x * 32;
    const float4* src4 = (const float4*)(cb + (size_t)R0 * ND);
#pragma unroll 4
    for (int it = 0; it < 16; it++) {
        int idx = it * 256 + tid;
        int row = idx >> 7, c4 = idx & 127;  // 128 float4 per row
        float4 v = src4[(size_t)row * 128 + c4];  // fully coalesced
        ushort4 o;
        o.x = f2bf(v.x); o.y = f2bf(v.y); o.z = f2bf(v.z); o.w = f2bf(v.w);
        *(ushort4*)&ct[row * CPAD + c4 * 4] = o;
        red[row][tid & 127] = v.x * v.x + v.y * v.y + v.z * v.z + v.w * v.w;  // unique slot per (it,tid)
    }
    __syncthreads();
    // norms: row = tid>>3, seg = tid&7 sums 16 slots, then 3-step shfl
    {
        int row = tid >> 3, seg = tid & 7;
        float s = 0.0f;
#pragma unroll
        for (int i = 0; i < 16; i++) s += red[row][seg * 16 + i];
        s += __shfl_xor(s, 1); s += __shfl_xor(s, 2); s += __shfl_xor(s, 4);
        if (seg == 0) cnorm[R0 + row] = s;
    }
    // swizzled chunk writes: wave w emits chunks w*8 .. w*8+7
    const int wave = tid >> 6, lane = tid & 63, l31 = lane & 31, half = lane >> 5;
    const int N_ = R0 >> 7, g = (R0 >> 5) & 3;
#pragma unroll
    for (int cc = 0; cc < 8; cc++) {
        int chunk = wave * 8 + cc;
        int K_ = chunk >> 2, ks = chunk & 3;
        uint4 v = *(const uint4*)&ct[l31 * CPAD + K_ * 64 + ks * 16 + half * 8];
        char* dst = (char*)Cb + ((size_t)((N_ * 8 + K_) * 16 + g * 4 + ks)) * 1024 + lane * 16;
        *(uint4*)dst = v;
    }
}

// ---- kernel 3: main GEMM, 32x32x16 MFMA, swizzled staging, fused min-epilogue ----
__global__ __launch_bounds__(256, 2) void triplet_main(
    const unsigned short* __restrict__ Z, const unsigned short* __restrict__ Cb,
    const float* __restrict__ cnorm, const int* __restrict__ teacher,
    float* __restrict__ negpart, float* __restrict__ pospart) {
    __shared__ unsigned short As[BM * BK];  // 16 KB, swizzled operand image
    __shared__ unsigned short Bs[BN * BK];  // 16 KB

    const int m0 = blockIdx.y * BM;
    const int n0 = blockIdx.x * BN;
    const int tid = threadIdx.x;
    const int wave = tid >> 6, lane = tid & 63;
    const int wr = wave >> 1, wc = wave & 1;   // 2x2 waves, each 64x64
    const int l31 = lane & 31, half = lane >> 5;

    f32x16 acc[2][2] = {};

    // staging: 16 chunks of 1024 B per operand per K-tile; wave w DMAs chunks w*4..w*4+3
    const char* gA = (const char*)Z + (size_t)(blockIdx.y * 8) * 16384 + (wave * 4) * 1024 + lane * 16;
    const char* gB = (const char*)Cb + (size_t)(blockIdx.x * 8) * 16384 + (wave * 4) * 1024 + lane * 16;
    char* lA = (char*)As + wave * 4096;
    char* lB = (char*)Bs + wave * 4096;

    for (int kt = 0; kt < ND / BK; kt++) {
#pragma unroll
        for (int i = 0; i < 4; i++) {
            async_copy16(gA + i * 1024, lA + i * 1024);
            async_copy16(gB + i * 1024, lB + i * 1024);
        }
        gA += 16384; gB += 16384;
        __syncthreads();

#pragma unroll
        for (int ks = 0; ks < 4; ks++) {
            bf16x8 a[2], b[2];
#pragma unroll
            for (int mi = 0; mi < 2; mi++)
                a[mi] = *(const bf16x8*)&As[(((wr * 2 + mi) * 4 + ks) * 512) + lane * 8];
#pragma unroll
            for (int ni = 0; ni < 2; ni++)
                b[ni] = *(const bf16x8*)&Bs[(((wc * 2 + ni) * 4 + ks) * 512) + lane * 8];
#pragma unroll
            for (int mi = 0; mi < 2; mi++)
#pragma unroll
                for (int ni = 0; ni < 2; ni++)
                    acc[mi][ni] = __builtin_amdgcn_mfma_f32_32x32x16_bf16(a[mi], b[ni], acc[mi][ni], 0, 0, 0);
        }
        __syncthreads();
    }

    // epilogue: C/D layout col = lane&31, row = (reg&3) + 8*(reg>>2) + 4*(lane>>5)
    const float INF = __builtin_inff();
    float cn[2];
    int ncol[2];
#pragma unroll
    for (int ni = 0; ni < 2; ni++) {
        ncol[ni] = n0 + wc * 64 + ni * 32 + l31;
        cn[ni] = cnorm[ncol[ni]];
    }
    const int chunk = (n0 >> 6) + wc;

#pragma unroll
    for (int mi = 0; mi < 2; mi++) {
#pragma unroll
        for (int reg = 0; reg < 16; reg++) {
            int m = m0 + wr * 64 + mi * 32 + (reg & 3) + 8 * (reg >> 2) + 4 * half;
            int tch = teacher[m];
            float minv = INF, posv = INF;
#pragma unroll
            for (int ni = 0; ni < 2; ni++) {
                float val = cn[ni] - 2.0f * acc[mi][ni][reg];
                bool ist = (ncol[ni] == tch);
                minv = fminf(minv, ist ? INF : val);
                posv = fminf(posv, ist ? val : INF);
            }
#pragma unroll
            for (int off = 1; off < 32; off <<= 1) {  // stays within 32-lane half
                minv = fminf(minv, __shfl_xor(minv, off));
                posv = fminf(posv, __shfl_xor(posv, off));
            }
            if (l31 == 0) {
                negpart[(size_t)chunk * NM + m] = minv;
                pospart[(size_t)chunk * NM + m] = posv;
            }
        }
    }
}

// ---- kernel 4: per-row reduce (256 blocks x 256 thr; 4 chunk-groups/block) ----
__global__ void reduce_rows2(const float* __restrict__ negpart, const float* __restrict__ pospart,
                             const float* __restrict__ npart, const int* __restrict__ lengths,
                             float* __restrict__ blocksums) {
    const float INF = __builtin_inff();
    int t = threadIdx.x;
    int r = t & 63, g = t >> 6;
    int m = blockIdx.x * 64 + r;
    float minv = INF, posv = INF;
#pragma unroll 4
    for (int c = g * 16; c < g * 16 + 16; c++) {
        minv = fminf(minv, negpart[(size_t)c * NM + m]);  // coalesced across r
        posv = fminf(posv, pospart[(size_t)c * NM + m]);
    }
    float zn = npart[(size_t)(g * 2) * NM + m] + npart[(size_t)(g * 2 + 1) * NM + m];

    __shared__ float sneg[4][64], spos[4][64], szn[4][64];
    sneg[g][r] = minv; spos[g][r] = posv; szn[g][r] = zn;
    __syncthreads();
    if (g == 0) {
        minv = fminf(fminf(sneg[0][r], sneg[1][r]), fminf(sneg[2][r], sneg[3][r]));
        posv = fminf(fminf(spos[0][r], spos[1][r]), fminf(spos[2][r], spos[3][r]));
        zn = szn[0][r] + szn[1][r] + szn[2][r] + szn[3][r];
        float negd = sqrtf(fmaxf(zn + minv, 1e-12f));
        float posd = sqrtf(fmaxf(zn + posv, 1e-12f));
        float tri = fmaxf(posd - negd + MARGIN_F, 0.0f);
        int b = m >> 11;
        int tt = m & (NT - 1);
        int flen = lengths[b] / ENC_STRIDE;
        float val = (tt < flen) ? tri : 0.0f;
#pragma unroll
        for (int off = 1; off < 64; off <<= 1) val += __shfl_xor(val, off);
        if (r == 0) blocksums[blockIdx.x] = val;
    }
}

// ---- kernel 5: finalize over 256 block sums ----
__global__ void finalize(const float* __restrict__ blocksums, const int* __restrict__ lengths,
                         float* __restrict__ out) {
    int t = threadIdx.x;  // 256
    float s = blocksums[t];
#pragma unroll
    for (int off = 1; off < 64; off <<= 1) s += __shfl_xor(s, off);
    __shared__ float red[4];
    int lane = t & 63, w = t >> 6;
    if (lane == 0) red[w] = s;
    __syncthreads();
    if (t == 0) {
        float cnt = 0.0f;
        for (int b = 0; b < NB; b++) cnt += (float)(lengths[b] / ENC_STRIDE);
        out[0] = (red[0] + red[1] + red[2] + red[3]) / (cnt + 1e-8f);
    }
}

extern "C" void kernel_launch(void* const* d_in, const int* in_sizes, int n_in,
                              void* d_out, int out_size, void* d_ws, size_t ws_size,
                              hipStream_t stream) {
    const float* sf = (const float*)d_in[0];
    const int* teacher = (const int*)d_in[1];
    const float* cb = (const float*)d_in[2];
    const int* lengths = (const int*)d_in[3];

    char* ws = (char*)d_ws;
    unsigned short* Z = (unsigned short*)(ws);                 // 16,777,216 B (swizzled)
    unsigned short* Cb = (unsigned short*)(ws + 16777216);     //  4,194,304 B (swizzled)
    float* cnorm = (float*)(ws + 20971520);                    //     16,384 B
    float* npart = (float*)(ws + 20987904);                    //    524,288 B (8 x NM)
    float* negpart = (float*)(ws + 21512192);                  //  4,194,304 B
    float* pospart = (float*)(ws + 25706496);                  //  4,194,304 B
    float* blocksums = (float*)(ws + 29900800);                //      1,024 B

    student_swz<<<dim3(NT / 32, ND / 64, NB), 256, 0, stream>>>(sf, Z, npart);
    codebook_swz<<<NCODES / 32, 256, 0, stream>>>(cb, Cb, cnorm);
    triplet_main<<<dim3(NCODES / BN, NM / BM), 256, 0, stream>>>(Z, Cb, cnorm, teacher, negpart, pospart);
    reduce_rows2<<<NM / 64, 256, 0, stream>>>(negpart, pospart, npart, lengths, blocksums);
    finalize<<<1, 256, 0, stream>>>(blocksums, lengths, (float*)d_out);
}

// Round 4
// 177.056 us; speedup vs baseline: 1.2053x; 1.2053x over previous
//
#include <hip/hip_runtime.h>
#include <hip/hip_bf16.h>

typedef __bf16 bf16x8 __attribute__((ext_vector_type(8)));
typedef float f32x4 __attribute__((ext_vector_type(4)));

#define NB 8
#define ND 512
#define NT 2048
#define NCODES 4096
#define NM (NB * NT)          // 16384 rows
#define MARGIN_F 0.2f
#define ENC_STRIDE 320

#define NQ 8                  // n-groups (grid.x); each block covers 512 n
#define NTILES 4              // n-tiles of 128 per block
#define NSLOT 16              // nq*2 + wc partial slots

// Chunk = 16 rows x 32 k bf16 = 1024 B; lane l holds row (l&15), k (l>>4)*8+j
// == the exact v_mfma_f32_16x16x32_bf16 A/B fragment image.
// Tile (R_, K_) = 128 rows x 64 k = 16 chunks, chunk id c = rg*2 + ks
// (rg = 16-row group 0..7, ks = 32-k step 0..1).
// Z tile base byte = (M_*8 + K_)*16384 ; Cb tile base = (N_*8 + K_)*16384.

static __device__ inline unsigned short f2bf(float v) {
    __hip_bfloat16 h = __float2bfloat16(v);
    return __builtin_bit_cast(unsigned short, h);
}

static __device__ inline void async_copy16(const void* g, void* l) {
    __builtin_amdgcn_global_load_lds(
        (const __attribute__((address_space(1))) unsigned int*)g,
        (__attribute__((address_space(3))) unsigned int*)l, 16, 0, 0);
}

// ---- kernel 1: student (B,D,T) fp32 -> swizzled Z bf16, + partial norms ----
__global__ void student_swz(const float* __restrict__ sf, unsigned short* __restrict__ Z,
                            float* __restrict__ npart) {
    __shared__ float tile[64][38];  // [d_local][t_local]; 38: float2-aligned, 2-way-only on reads
    __shared__ float red[4][16];
    const int b = blockIdx.z;
    const int t0 = blockIdx.x * 32;
    const int d0 = blockIdx.y * 64;
    const int tid = threadIdx.x;  // 256
    const float* src = sf + (size_t)b * ND * NT;
#pragma unroll
    for (int p = 0; p < 2; p++) {
        int d = p * 32 + (tid >> 3);
        int t4 = (tid & 7) * 4;
        float4 v = *(const float4*)(src + (size_t)(d0 + d) * NT + t0 + t4);  // coalesced
        *(float2*)&tile[d][t4] = make_float2(v.x, v.y);
        *(float2*)&tile[d][t4 + 2] = make_float2(v.z, v.w);
    }
    __syncthreads();
    // wave w = rgl*2 + ks emits chunk (rg0+rgl, ks); lane l: row rgl*16+(l&15), k ks*32+(l>>4)*8+q
    const int wave = tid >> 6, lane = tid & 63, l15 = lane & 15, kq = lane >> 4;
    const int rgl = wave >> 1, ks = wave & 1;
    float sq = 0.0f;
    unsigned short o[8];
#pragma unroll
    for (int q = 0; q < 8; q++) {
        float v = tile[ks * 32 + kq * 8 + q][rgl * 16 + l15];
        sq += v * v;
        o[q] = f2bf(v);
    }
    const int mrow0 = b * NT + t0;  // multiple of 32
    const int M_ = mrow0 >> 7;
    const int rg = ((mrow0 >> 4) & 7) + rgl;
    const int K_ = d0 >> 6;
    char* dst = (char*)Z + ((size_t)(M_ * 8 + K_) * 16 + rg * 2 + ks) * 1024 + lane * 16;
    *(uint4*)dst = *(uint4*)o;  // coalesced 1024-B chunk per wave
    // norms: combine 4 kq-subgroups (lane bits 4,5), then ks pairs via LDS
    sq += __shfl_xor(sq, 16);
    sq += __shfl_xor(sq, 32);
    if (lane < 16) red[wave][l15] = sq;
    __syncthreads();
    if (tid < 32) {
        int r = tid & 15, g = tid >> 4;
        float zn = red[g * 2][r] + red[g * 2 + 1][r];
        npart[(size_t)(d0 >> 6) * NM + mrow0 + g * 16 + r] = zn;
    }
}

// ---- kernel 2: codebook (NC,D) fp32 -> swizzled Cb bf16, + row norms ----
#define CPAD 520  // ushorts per row (1040 B: 16B-aligned)
__global__ void codebook_swz(const float* __restrict__ cb, unsigned short* __restrict__ Cb,
                             float* __restrict__ cnorm) {
    __shared__ unsigned short ct[16 * CPAD];  // 16.6 KB
    __shared__ float red[16][128];            // 8 KB
    const int tid = threadIdx.x;  // 256
    const int R0 = blockIdx.x * 16;
    const float4* src4 = (const float4*)(cb + (size_t)R0 * ND);
#pragma unroll
    for (int it = 0; it < 8; it++) {
        int idx = it * 256 + tid;
        int row = idx >> 7, c4 = idx & 127;  // unique (row,c4) per idx
        float4 v = src4[(size_t)row * 128 + c4];  // fully coalesced
        ushort4 o;
        o.x = f2bf(v.x); o.y = f2bf(v.y); o.z = f2bf(v.z); o.w = f2bf(v.w);
        *(ushort4*)&ct[row * CPAD + c4 * 4] = o;
        red[row][c4] = v.x * v.x + v.y * v.y + v.z * v.z + v.w * v.w;
    }
    __syncthreads();
    if (tid < 128) {
        int row = tid >> 3, seg = tid & 7;
        float s = 0.0f;
#pragma unroll
        for (int i = 0; i < 16; i++) s += red[row][seg * 16 + i];
        s += __shfl_xor(s, 1); s += __shfl_xor(s, 2); s += __shfl_xor(s, 4);
        if (seg == 0) cnorm[R0 + row] = s;
    }
    // emit 16 chunks (K_ 0..7 x ks 0..1); wave w does ci = w*4..w*4+3
    const int wave = tid >> 6, lane = tid & 63, l15 = lane & 15, kq = lane >> 4;
    const int N_ = R0 >> 7, rg = (R0 >> 4) & 7;
#pragma unroll
    for (int cc = 0; cc < 4; cc++) {
        int ci = wave * 4 + cc;
        int K_ = ci >> 1, ks = ci & 1;
        uint4 v = *(const uint4*)&ct[l15 * CPAD + K_ * 64 + ks * 32 + kq * 8];
        char* dst = (char*)Cb + ((size_t)(N_ * 8 + K_) * 16 + rg * 2 + ks) * 1024 + lane * 16;
        *(uint4*)dst = v;  // coalesced
    }
}

// ---- kernel 3: main GEMM, 16x16x32 MFMA 4x4/wave, swizzled chunks, n-loop + running min ----
__global__ __launch_bounds__(256, 2) void triplet_main(
    const unsigned short* __restrict__ Z, const unsigned short* __restrict__ Cb,
    const float* __restrict__ cnorm, const int* __restrict__ teacher,
    float* __restrict__ negq, float* __restrict__ posq) {
    __shared__ unsigned short As[128 * 64];  // 16 KB swizzled chunk image
    __shared__ unsigned short Bs[128 * 64];  // 16 KB

    const int nq = blockIdx.x;   // 0..7
    const int M_ = blockIdx.y;   // 0..127
    const int m0 = M_ * 128;
    const int tid = threadIdx.x;
    const int wave = tid >> 6, lane = tid & 63;
    const int wr = wave >> 1, wc = wave & 1;
    const int l15 = lane & 15, quad = lane >> 4;

    const float INF = __builtin_inff();
    float minv[4][4], posv[4][4];
    int tch[4][4];
#pragma unroll
    for (int mi = 0; mi < 4; mi++)
#pragma unroll
        for (int r = 0; r < 4; r++) {
            minv[mi][r] = INF;
            posv[mi][r] = INF;
            tch[mi][r] = teacher[m0 + wr * 64 + mi * 16 + quad * 4 + r];  // broadcast load
        }

    char* lA = (char*)As + wave * 4096;
    char* lB = (char*)Bs + wave * 4096;
    const char* gAbase = (const char*)Z + (size_t)M_ * 8 * 16384 + wave * 4096 + lane * 16;

    for (int nt = 0; nt < NTILES; nt++) {
        const int N_ = nq * NTILES + nt;  // 0..31
        const int n0 = N_ * 128;
        const char* gB = (const char*)Cb + (size_t)N_ * 8 * 16384 + wave * 4096 + lane * 16;
        const char* gA = gAbase;
        f32x4 acc[4][4] = {};

        for (int kt = 0; kt < 8; kt++) {
#pragma unroll
            for (int i = 0; i < 4; i++) {
                async_copy16(gA + i * 1024, lA + i * 1024);
                async_copy16(gB + i * 1024, lB + i * 1024);
            }
            gA += 16384; gB += 16384;
            __syncthreads();
#pragma unroll
            for (int ks = 0; ks < 2; ks++) {
                bf16x8 a[4], b[4];
#pragma unroll
                for (int mi = 0; mi < 4; mi++)
                    a[mi] = *(const bf16x8*)&As[(((wr * 4 + mi) * 2 + ks) * 512) + lane * 8];
#pragma unroll
                for (int ni = 0; ni < 4; ni++)
                    b[ni] = *(const bf16x8*)&Bs[(((wc * 4 + ni) * 2 + ks) * 512) + lane * 8];
#pragma unroll
                for (int mi = 0; mi < 4; mi++)
#pragma unroll
                    for (int ni = 0; ni < 4; ni++)
                        acc[mi][ni] = __builtin_amdgcn_mfma_f32_16x16x32_bf16(a[mi], b[ni], acc[mi][ni], 0, 0, 0);
            }
            __syncthreads();
        }

        // fold this 128-col tile into the running per-row min (registers only)
        float cn[4]; int col[4];
#pragma unroll
        for (int ni = 0; ni < 4; ni++) {
            col[ni] = n0 + wc * 64 + ni * 16 + l15;
            cn[ni] = cnorm[col[ni]];
        }
#pragma unroll
        for (int mi = 0; mi < 4; mi++)
#pragma unroll
            for (int r = 0; r < 4; r++) {
                int t = tch[mi][r];
#pragma unroll
                for (int ni = 0; ni < 4; ni++) {
                    float val = fmaf(-2.0f, acc[mi][ni][r], cn[ni]);
                    bool ist = (col[ni] == t);
                    minv[mi][r] = fminf(minv[mi][r], ist ? INF : val);
                    posv[mi][r] = ist ? val : posv[mi][r];
                }
            }
    }

    // once per block: cross-lane min over the 16 columns sharing a row, write slot
    const int slot = nq * 2 + wc;  // 0..15
#pragma unroll
    for (int mi = 0; mi < 4; mi++)
#pragma unroll
        for (int r = 0; r < 4; r++) {
            float mn = minv[mi][r], ps = posv[mi][r];
#pragma unroll
            for (int off = 1; off < 16; off <<= 1) {
                mn = fminf(mn, __shfl_xor(mn, off));
                ps = fminf(ps, __shfl_xor(ps, off));
            }
            if (l15 == 0) {
                int m = m0 + wr * 64 + mi * 16 + quad * 4 + r;
                negq[(size_t)slot * NM + m] = mn;
                posq[(size_t)slot * NM + m] = ps;
            }
        }
}

// ---- kernel 4: per-row reduce over 16 slots -> masked triplet block sums ----
__global__ void reduce_final(const float* __restrict__ negq, const float* __restrict__ posq,
                             const float* __restrict__ npart, const int* __restrict__ lengths,
                             float* __restrict__ blocksums) {
    const float INF = __builtin_inff();
    int m = blockIdx.x * 256 + threadIdx.x;
    float mn = INF, ps = INF;
#pragma unroll
    for (int s = 0; s < NSLOT; s++) {
        mn = fminf(mn, negq[(size_t)s * NM + m]);  // coalesced
        ps = fminf(ps, posq[(size_t)s * NM + m]);
    }
    float zn = 0.0f;
#pragma unroll
    for (int j = 0; j < 8; j++) zn += npart[(size_t)j * NM + m];
    float negd = sqrtf(fmaxf(zn + mn, 1e-12f));
    float posd = sqrtf(fmaxf(zn + ps, 1e-12f));
    float tri = fmaxf(posd - negd + MARGIN_F, 0.0f);
    int b = m >> 11;
    int tt = m & (NT - 1);
    int flen = lengths[b] / ENC_STRIDE;
    float val = (tt < flen) ? tri : 0.0f;

    __shared__ float red[4];
#pragma unroll
    for (int off = 1; off < 64; off <<= 1) val += __shfl_xor(val, off);
    int lane = threadIdx.x & 63, w = threadIdx.x >> 6;
    if (lane == 0) red[w] = val;
    __syncthreads();
    if (threadIdx.x == 0) blocksums[blockIdx.x] = red[0] + red[1] + red[2] + red[3];
}

// ---- kernel 5: finalize over 64 block sums ----
__global__ void finalize(const float* __restrict__ blocksums, const int* __restrict__ lengths,
                         float* __restrict__ out) {
    float s = blocksums[threadIdx.x];  // 64 threads
#pragma unroll
    for (int off = 1; off < 64; off <<= 1) s += __shfl_xor(s, off);
    if (threadIdx.x == 0) {
        float cnt = 0.0f;
        for (int b = 0; b < NB; b++) cnt += (float)(lengths[b] / ENC_STRIDE);
        out[0] = s / (cnt + 1e-8f);
    }
}

extern "C" void kernel_launch(void* const* d_in, const int* in_sizes, int n_in,
                              void* d_out, int out_size, void* d_ws, size_t ws_size,
                              hipStream_t stream) {
    const float* sf = (const float*)d_in[0];
    const int* teacher = (const int*)d_in[1];
    const float* cb = (const float*)d_in[2];
    const int* lengths = (const int*)d_in[3];

    char* ws = (char*)d_ws;
    unsigned short* Z = (unsigned short*)(ws);               // 16,777,216 B (swizzled)
    unsigned short* Cb = (unsigned short*)(ws + 16777216);   //  4,194,304 B (swizzled)
    float* cnorm = (float*)(ws + 20971520);                  //     16,384 B
    float* npart = (float*)(ws + 20987904);                  //    524,288 B (8 x NM)
    float* negq = (float*)(ws + 21512192);                   //  1,048,576 B (16 x NM)
    float* posq = (float*)(ws + 22560768);                   //  1,048,576 B
    float* blocksums = (float*)(ws + 23609344);              //        256 B

    student_swz<<<dim3(NT / 32, ND / 64, NB), 256, 0, stream>>>(sf, Z, npart);
    codebook_swz<<<NCODES / 16, 256, 0, stream>>>(cb, Cb, cnorm);
    triplet_main<<<dim3(NQ, NM / 128), 256, 0, stream>>>(Z, Cb, cnorm, teacher, negq, posq);
    reduce_final<<<NM / 256, 256, 0, stream>>>(negq, posq, npart, lengths, blocksums);
    finalize<<<1, 64, 0, stream>>>(blocksums, lengths, (float*)d_out);
}

// Round 5
// 151.000 us; speedup vs baseline: 1.4133x; 1.1726x over previous
//
#include <hip/hip_runtime.h>
#include <hip/hip_bf16.h>

typedef __bf16 bf16x8 __attribute__((ext_vector_type(8)));
typedef float f32x4 __attribute__((ext_vector_type(4)));
typedef int v8i __attribute__((ext_vector_type(8)));

#define NB 8
#define ND 512
#define NT 2048
#define NCODES 4096
#define NM (NB * NT)
#define MARGIN_F 0.2f
#define ENC_STRIDE 320

// MX fragment image (Zq, Cq), fp8 e4m3:
//   tile (R_, K_) = 128 rows x 128 k = 16 KB at ((R_*4 + K_) * 16384)
//   fragment rg (0..7) = 16 rows x 128 k = 2048 B at rg*2048 within tile
//   bytes [0,1024): lane l's 16 B at l*16 = row rg*16+(l&15), k = (l>>4)*32 + 0..15
//   bytes [1024,2048): same lanes, k = (l>>4)*32 + 16..31
// => fragment = 2 contiguous 1024-B global_load_lds ops; frag read = 2 ds_read_b128
//    at (base + lane*16) and (+1024): conflict-free.

static __device__ inline unsigned short f2bf(float v) {
    __hip_bfloat16 h = __float2bfloat16(v);
    return __builtin_bit_cast(unsigned short, h);
}

static __device__ inline void async_copy16(const void* g, void* l) {
    __builtin_amdgcn_global_load_lds(
        (const __attribute__((address_space(1))) unsigned int*)g,
        (__attribute__((address_space(3))) unsigned int*)l, 16, 0, 0);
}

// ---- kernel 1: student (B,D,T) fp32 -> fp8 fragment image Zq + bf16 row-major Zrm ----
__global__ void student_prep(const float* __restrict__ sf, unsigned char* __restrict__ Zq,
                             unsigned short* __restrict__ Zrm) {
    __shared__ float tile[128][65];  // [d_local][t_local]
    const int b = blockIdx.z;
    const int t0 = blockIdx.x * 64;
    const int d0 = blockIdx.y * 128;
    const int tid = threadIdx.x;  // 256
    const float* src = sf + (size_t)b * ND * NT;
#pragma unroll
    for (int it = 0; it < 8; it++) {
        int idx = it * 256 + tid;
        int d = idx >> 4, t4 = (idx & 15) * 4;
        float4 v = *(const float4*)(src + (size_t)(d0 + d) * NT + t0 + t4);  // coalesced
        tile[d][t4] = v.x; tile[d][t4 + 1] = v.y; tile[d][t4 + 2] = v.z; tile[d][t4 + 3] = v.w;
    }
    __syncthreads();
    const int wave = tid >> 6, lane = tid & 63, l15 = lane & 15, kq = lane >> 4;
    const int m0 = b * NT + t0;
    // fp8 fragment emit: wave w -> fragment rg0+w; lane: row w*16+l15, k kq*32+j
    {
        const int trow = wave * 16 + l15;
        unsigned char q[32];
#pragma unroll
        for (int j = 0; j < 32; j += 2) {
            float a = tile[kq * 32 + j][trow];
            float c = tile[kq * 32 + j + 1][trow];
            int p = __builtin_amdgcn_cvt_pk_fp8_f32(a, c, 0, false);
            q[j] = (unsigned char)(p & 0xFF);
            q[j + 1] = (unsigned char)((p >> 8) & 0xFF);
        }
        const int M_ = m0 >> 7, rg = ((m0 >> 4) & 7) + wave, K_ = d0 >> 7;
        char* base = (char*)Zq + ((size_t)((M_ * 4 + K_) * 8 + rg)) * 2048;
        *(uint4*)(base + lane * 16) = *(uint4*)&q[0];
        *(uint4*)(base + 1024 + lane * 16) = *(uint4*)&q[16];
    }
    // bf16 row-major emit for the refine kernel
    {
        int t = tid >> 2;
#pragma unroll
        for (int it = 0; it < 8; it++) {
            int d = (tid & 3) * 4 + it * 16;
            ushort4 o;
            o.x = f2bf(tile[d][t]); o.y = f2bf(tile[d + 1][t]);
            o.z = f2bf(tile[d + 2][t]); o.w = f2bf(tile[d + 3][t]);
            *(ushort4*)(Zrm + (size_t)(m0 + t) * ND + d0 + d) = o;
        }
    }
}

// ---- kernel 2: codebook fp32 -> fp8 fragment image Cq ----
__global__ void codebook_fp8(const float* __restrict__ cb, unsigned char* __restrict__ Cq) {
    const int tid = threadIdx.x, wave = tid >> 6, lane = tid & 63, l15 = lane & 15, kq = lane >> 4;
    const int r0 = blockIdx.x * 64, K_ = blockIdx.y;
    const int row = r0 + wave * 16 + l15;
    const float* srcr = cb + (size_t)row * ND + K_ * 128 + kq * 32;
    unsigned char q[32];
#pragma unroll
    for (int j4 = 0; j4 < 8; j4++) {
        float4 v = *(const float4*)(srcr + j4 * 4);
        int p0 = __builtin_amdgcn_cvt_pk_fp8_f32(v.x, v.y, 0, false);
        int p1 = __builtin_amdgcn_cvt_pk_fp8_f32(v.z, v.w, 0, false);
        q[j4 * 4 + 0] = (unsigned char)(p0 & 0xFF);
        q[j4 * 4 + 1] = (unsigned char)((p0 >> 8) & 0xFF);
        q[j4 * 4 + 2] = (unsigned char)(p1 & 0xFF);
        q[j4 * 4 + 3] = (unsigned char)((p1 >> 8) & 0xFF);
    }
    const int N_ = r0 >> 7, rg = ((r0 >> 4) & 7) + wave;
    char* base = (char*)Cq + ((size_t)((N_ * 4 + K_) * 8 + rg)) * 2048;
    *(uint4*)(base + lane * 16) = *(uint4*)&q[0];
    *(uint4*)(base + 1024 + lane * 16) = *(uint4*)&q[16];
}

// ---- kernel 3: codebook row norms (fp32) ----
__global__ void cnorm_k(const float* __restrict__ cb, float* __restrict__ cnorm) {
    int wave = threadIdx.x >> 6, lane = threadIdx.x & 63;
    int row = blockIdx.x * 4 + wave;
    const float* src = cb + (size_t)row * ND + lane * 8;
    float s = 0.0f;
#pragma unroll
    for (int i = 0; i < 2; i++) {
        float4 v = *(const float4*)(src + i * 4);
        s += v.x * v.x + v.y * v.y + v.z * v.z + v.w * v.w;
    }
#pragma unroll
    for (int off = 1; off < 64; off <<= 1) s += __shfl_xor(s, off);
    if (lane == 0) cnorm[row] = s;
}

// ---- kernel 4: MX-fp8 GEMM, argmin of (cnorm - 2*dot), teacher excluded ----
__global__ __launch_bounds__(256, 2) void triplet_main(
    const unsigned char* __restrict__ Zq, const unsigned char* __restrict__ Cq,
    const float* __restrict__ cnorm, const int* __restrict__ teacher,
    unsigned int* __restrict__ minq) {
    __shared__ __align__(16) unsigned char As[16384];
    __shared__ __align__(16) unsigned char Bs[16384];

    const int M_ = blockIdx.x;   // 0..127 (x-major => XCD = M_ % 8: strip-local L2 reuse)
    const int nq = blockIdx.y;   // 0..7
    const int m0 = M_ * 128;
    const int tid = threadIdx.x;
    const int wave = tid >> 6, lane = tid & 63;
    const int wr = wave >> 1, wc = wave & 1;
    const int l15 = lane & 15, quad = lane >> 4;

    unsigned int minu[4][4];
    int tch[4][4];
#pragma unroll
    for (int mi = 0; mi < 4; mi++)
#pragma unroll
        for (int r = 0; r < 4; r++) {
            minu[mi][r] = 0xFFFFFFFFu;
            tch[mi][r] = teacher[m0 + wr * 64 + mi * 16 + quad * 4 + r];
        }

    const char* gA0 = (const char*)Zq + (size_t)M_ * 4 * 16384 + wave * 4096 + lane * 16;
    char* lA = (char*)As + wave * 4096;
    char* lB = (char*)Bs + wave * 4096;

    for (int nt = 0; nt < 4; nt++) {
        const int N_ = nq * 4 + nt;
        const int n0 = N_ * 128;
        const char* gA = gA0;
        const char* gB = (const char*)Cq + (size_t)N_ * 4 * 16384 + wave * 4096 + lane * 16;
        f32x4 acc[4][4] = {};

        for (int kt = 0; kt < 4; kt++) {
#pragma unroll
            for (int i = 0; i < 4; i++) {
                async_copy16(gA + i * 1024, lA + i * 1024);
                async_copy16(gB + i * 1024, lB + i * 1024);
            }
            gA += 16384; gB += 16384;
            __syncthreads();

            v8i av[4], bv[4];
#pragma unroll
            for (int mi = 0; mi < 4; mi++) {
                int rg = wr * 4 + mi;
                union { uint4 q[2]; v8i v; } u;
                u.q[0] = *(const uint4*)(As + rg * 2048 + lane * 16);
                u.q[1] = *(const uint4*)(As + rg * 2048 + 1024 + lane * 16);
                av[mi] = u.v;
            }
#pragma unroll
            for (int ni = 0; ni < 4; ni++) {
                int rg = wc * 4 + ni;
                union { uint4 q[2]; v8i v; } u;
                u.q[0] = *(const uint4*)(Bs + rg * 2048 + lane * 16);
                u.q[1] = *(const uint4*)(Bs + rg * 2048 + 1024 + lane * 16);
                bv[ni] = u.v;
            }
#pragma unroll
            for (int mi = 0; mi < 4; mi++)
#pragma unroll
                for (int ni = 0; ni < 4; ni++)
                    acc[mi][ni] = __builtin_amdgcn_mfma_scale_f32_16x16x128_f8f6f4(
                        av[mi], bv[ni], acc[mi][ni], 0, 0,
                        0, 0x7F7F7F7F, 0, 0x7F7F7F7F);  // scales = 1.0 (e8m0 127)
            __syncthreads();
        }

        // fold: packed umin of (val-bits | col), teacher excluded
        float cn[4]; int col[4];
#pragma unroll
        for (int ni = 0; ni < 4; ni++) {
            col[ni] = n0 + wc * 64 + ni * 16 + l15;
            cn[ni] = cnorm[col[ni]];
        }
#pragma unroll
        for (int mi = 0; mi < 4; mi++)
#pragma unroll
            for (int r = 0; r < 4; r++) {
                int t = tch[mi][r];
#pragma unroll
                for (int ni = 0; ni < 4; ni++) {
                    float val = fmaxf(fmaf(-2.0f, acc[mi][ni][r], cn[ni]), 0.0f);
                    unsigned int u = (__builtin_bit_cast(unsigned int, val) & 0xFFFFF000u)
                                     | (unsigned int)col[ni];
                    u = (col[ni] == t) ? 0xFFFFFFFFu : u;
                    minu[mi][r] = min(minu[mi][r], u);
                }
            }
    }

    const int slot = nq * 2 + wc;  // 0..15
#pragma unroll
    for (int mi = 0; mi < 4; mi++)
#pragma unroll
        for (int r = 0; r < 4; r++) {
            unsigned int u = minu[mi][r];
#pragma unroll
            for (int off = 1; off < 16; off <<= 1) u = min(u, (unsigned int)__shfl_xor((int)u, off));
            if (l15 == 0) {
                int m = m0 + wr * 64 + mi * 16 + quad * 4 + r;
                minq[(size_t)slot * NM + m] = u;
            }
        }
}

// ---- kernel 5: refine — exact pos/neg distances + masked triplet partial sums ----
__global__ void refine(const unsigned short* __restrict__ Zrm, const float* __restrict__ cb,
                       const unsigned int* __restrict__ minq, const int* __restrict__ teacher,
                       const int* __restrict__ lengths, float* __restrict__ blocksums) {
    const int tid = threadIdx.x, wave = tid >> 6, lane = tid & 63;
    const int m = blockIdx.x * 4 + wave;
    // combine the 16 slot argmins
    unsigned int u = minq[(size_t)(lane & 15) * NM + m];
    u = min(u, (unsigned int)__shfl_xor((int)u, 1));
    u = min(u, (unsigned int)__shfl_xor((int)u, 2));
    u = min(u, (unsigned int)__shfl_xor((int)u, 4));
    u = min(u, (unsigned int)__shfl_xor((int)u, 8));
    const int ng = (int)(u & 0xFFFu);
    const int tch = teacher[m];
    // exact distances: bf16 z, fp32 codebook
    bf16x8 z8 = *(const bf16x8*)(Zrm + (size_t)m * ND + lane * 8);
    const float* cn_ = cb + (size_t)ng * ND + lane * 8;
    const float* ct_ = cb + (size_t)tch * ND + lane * 8;
    float an = 0.0f, at = 0.0f;
#pragma unroll
    for (int i = 0; i < 2; i++) {
        float4 vn = *(const float4*)(cn_ + i * 4);
        float4 vt = *(const float4*)(ct_ + i * 4);
        float z0 = (float)z8[i * 4 + 0], z1 = (float)z8[i * 4 + 1];
        float z2 = (float)z8[i * 4 + 2], z3 = (float)z8[i * 4 + 3];
        float d;
        d = z0 - vn.x; an += d * d;  d = z0 - vt.x; at += d * d;
        d = z1 - vn.y; an += d * d;  d = z1 - vt.y; at += d * d;
        d = z2 - vn.z; an += d * d;  d = z2 - vt.z; at += d * d;
        d = z3 - vn.w; an += d * d;  d = z3 - vt.w; at += d * d;
    }
#pragma unroll
    for (int off = 1; off < 64; off <<= 1) {
        an += __shfl_xor(an, off);
        at += __shfl_xor(at, off);
    }
    __shared__ float red[4];
    if (lane == 0) {
        float negd = sqrtf(fmaxf(an, 1e-12f));
        float posd = sqrtf(fmaxf(at, 1e-12f));
        float tri = fmaxf(posd - negd + MARGIN_F, 0.0f);
        int t = m & (NT - 1);
        int b = m >> 11;
        int flen = lengths[b] / ENC_STRIDE;
        red[wave] = (t < flen) ? tri : 0.0f;
    }
    __syncthreads();
    if (tid == 0) blocksums[blockIdx.x] = red[0] + red[1] + red[2] + red[3];
}

// ---- kernel 6: finalize over 4096 block sums ----
__global__ void finalize(const float* __restrict__ blocksums, const int* __restrict__ lengths,
                         float* __restrict__ out) {
    int tid = threadIdx.x;  // 256
    float s = 0.0f;
#pragma unroll
    for (int i = 0; i < 16; i++) s += blocksums[tid + i * 256];
#pragma unroll
    for (int off = 1; off < 64; off <<= 1) s += __shfl_xor(s, off);
    __shared__ float red[4];
    int lane = tid & 63, w = tid >> 6;
    if (lane == 0) red[w] = s;
    __syncthreads();
    if (tid == 0) {
        float cnt = 0.0f;
        for (int b = 0; b < NB; b++) cnt += (float)(lengths[b] / ENC_STRIDE);
        out[0] = (red[0] + red[1] + red[2] + red[3]) / (cnt + 1e-8f);
    }
}

extern "C" void kernel_launch(void* const* d_in, const int* in_sizes, int n_in,
                              void* d_out, int out_size, void* d_ws, size_t ws_size,
                              hipStream_t stream) {
    const float* sf = (const float*)d_in[0];
    const int* teacher = (const int*)d_in[1];
    const float* cb = (const float*)d_in[2];
    const int* lengths = (const int*)d_in[3];

    char* ws = (char*)d_ws;
    unsigned char* Zq = (unsigned char*)(ws);                  //  8,388,608 B
    unsigned char* Cq = (unsigned char*)(ws + 8388608);        //  2,097,152 B
    unsigned short* Zrm = (unsigned short*)(ws + 10485760);    // 16,777,216 B
    float* cnorm = (float*)(ws + 27262976);                    //     16,384 B
    unsigned int* minq = (unsigned int*)(ws + 27279360);       //  1,048,576 B
    float* blocksums = (float*)(ws + 28327936);                //     16,384 B

    student_prep<<<dim3(NT / 64, ND / 128, NB), 256, 0, stream>>>(sf, Zq, Zrm);
    codebook_fp8<<<dim3(NCODES / 64, 4), 256, 0, stream>>>(cb, Cq);
    cnorm_k<<<NCODES / 4, 256, 0, stream>>>(cb, cnorm);
    triplet_main<<<dim3(128, 8), 256, 0, stream>>>(Zq, Cq, cnorm, teacher, minq);
    refine<<<NM / 4, 256, 0, stream>>>(Zrm, cb, minq, teacher, lengths, blocksums);
    finalize<<<1, 256, 0, stream>>>(blocksums, lengths, (float*)d_out);
}